// Round 8
// baseline (460.815 us; speedup 1.0000x reference)
//
#include <hip/hip_runtime.h>
#include <math.h>

// Problem constants
#define BB   128
#define LL   512
#define CC   321
#define PREDD 336
// Seasonal MLP: rows = B*C*S = 164352, dims 128 -> 512 -> 128 (x2 blocks)

using bf16x8  = __attribute__((ext_vector_type(8))) __bf16;
using floatx4 = __attribute__((ext_vector_type(4))) float;
using uintx4  = __attribute__((ext_vector_type(4))) unsigned int;
using uintx2  = __attribute__((ext_vector_type(2))) unsigned int;
typedef unsigned short u16;
typedef unsigned int u32;

#define MFMA16(a,b,c) __builtin_amdgcn_mfma_f32_16x16x32_bf16(a,b,c,0,0,0)

__device__ __forceinline__ u16 f2bf(float f){
    union { float f; unsigned u; } v; v.f = f;
    unsigned r = v.u + 0x7FFFu + ((v.u >> 16) & 1u);   // RNE
    return (u16)(r >> 16);
}
// pack two fp32 -> packed bf16 pair (RNE), lo16 = a
__device__ __forceinline__ u32 pack2bf(float a, float b){
    union { float f; u32 u; } x, y; x.f = a; y.f = b;
    u32 lo = (x.u + 0x7FFFu + ((x.u >> 16) & 1u)) >> 16;
    u32 hi = (y.u + 0x7FFFu + ((y.u >> 16) & 1u)) & 0xFFFF0000u;
    return hi | lo;
}

// tanh-GELU, sigmoid form: x * sigma(2u), 8 VALU ops.
__device__ __forceinline__ float fgelu(float x){
    float u = x*(0.7978845608f + 0.035677408f*x*x);
    float na = fminf(-2.8853900818f*u, 80.f);     // -2*log2(e)*u
    float t = __builtin_amdgcn_exp2f(na);
    return x*__builtin_amdgcn_rcpf(1.f + t);
}

__device__ __forceinline__ int swz64(int r, int s){ return r*64 + (((s ^ r) & 7) << 3); }

// async global->LDS DMA, 16B per lane; LDS dest = uniform base + lane*16.
__device__ __forceinline__ void dma16(const u16* g, const u16* l){
    __builtin_amdgcn_global_load_lds(
        (const __attribute__((address_space(1))) u32*)g,
        (__attribute__((address_space(3))) u32*)l, 16, 0, 0);
}

// ---------------- weight prep: fp32 -> bf16, pre-transposed [Ncols][K] ----------------
__global__ void prep_k(const float* __restrict__ W11, const float* __restrict__ W12,
                       const float* __restrict__ W21, const float* __restrict__ W22,
                       const float* __restrict__ Wtr, const float* __restrict__ Wse,
                       u16* __restrict__ BT1, u16* __restrict__ BT2,
                       u16* __restrict__ BT3, u16* __restrict__ BT4,
                       u16* __restrict__ BT5)
{
    int idx = blockIdx.x * 256 + threadIdx.x;
    if (idx < 65536){
        int h = idx >> 7, k = idx & 127;          // BT1/BT3: [512][128] = W11^T / W21^T
        BT1[idx] = f2bf(W11[k*512 + h]);
        BT3[idx] = f2bf(W21[k*512 + h]);
        int n = idx >> 9, k2 = idx & 511;         // BT2/BT4: [128][512] = W12^T / W22^T
        BT2[idx] = f2bf(W12[k2*128 + n]);
        BT4[idx] = f2bf(W22[k2*128 + n]);
    }
    if (idx < 393216){
        // BT5: [384][1024]; k<512 -> W_tr rows; k>=512 -> W_se rows permuted to (s,n)-major
        int p = idx >> 10, k = idx & 1023;
        float v = 0.f;
        if (p < PREDD){
            if (k < 512) v = Wtr[k*PREDD + p];
            else { int kk = k - 512; int s = kk >> 7; int n = kk & 127; v = Wse[(4*n + s)*PREDD + p]; }
        }
        BT5[idx] = f2bf(v);
    }
}

// ---------------- fused RevIN stats + moving-avg decomposition ----------------
#define XT(t,c) xt[((t)<<4) + (((t)>>5)<<1) + (c)]
__global__ __launch_bounds__(256) void decomp_k(
    const float* __restrict__ x, const float* __restrict__ rw, const float* __restrict__ rb,
    u16* __restrict__ Afin, u16* __restrict__ xs, float2* __restrict__ stats)
{
    __shared__ float xt[8240];
    __shared__ float red[2][16][16];
    __shared__ float sh_m[16], sh_istd[16];
    int b = blockIdx.x / 21, ct = blockIdx.x % 21;
    int tid = threadIdx.x;

    int cl = tid & 15, lp = tid >> 4;
    int c = ct*16 + cl;
    bool valid = c < CC;
    const float* xb = x + (size_t)b*LL*CC;
    float s = 0.f, q = 0.f;
    for (int i = 0; i < 32; ++i){
        int t = lp + 16*i;
        float v = valid ? xb[(size_t)t*CC + c] : 0.f;
        XT(t, cl) = v;
        s += v; q += v*v;
    }
    red[0][lp][cl] = s; red[1][lp][cl] = q;
    __syncthreads();
    if (tid < 16){
        float ss = 0.f, qq = 0.f;
        for (int j = 0; j < 16; ++j){ ss += red[0][j][tid]; qq += red[1][j][tid]; }
        float m  = ss * (1.f/512.f);
        float var = qq * (1.f/512.f) - m*m;
        float sd = sqrtf(var + 1e-5f);
        sh_m[tid] = m; sh_istd[tid] = 1.f/sd;
        int cc = ct*16 + tid;
        if (cc < CC) stats[(size_t)b*CC + cc] = make_float2(m, sd);
    }
    __syncthreads();

    int ch = tid >> 4, tp = tid & 15;
    int c2 = ct*16 + ch;
    if (c2 >= CC) return;
    float m = sh_m[ch], istd = sh_istd[ch];
    float w = rw[c2] * istd, bbv = rb[c2];
    size_t bc = (size_t)b*CC + c2;
    u16* tr  = Afin + bc*1024;
    u16* xsr = xs   + bc*512;
    int t0 = tp*32;

    float win = 0.f;
#pragma unroll
    for (int d = -12; d <= 12; ++d){
        int u = t0 + d; u = u < 0 ? 0 : (u > 511 ? 511 : u);
        win += XT(u, ch);
    }
    u16 trbuf[8];
    u16 xsbuf[4][8];
#pragma unroll
    for (int i = 0; i < 32; ++i){
        int t = t0 + i;
        float Ax = win * (1.f/25.f);
        float xv = XT(t, ch);
        trbuf[i & 7] = f2bf((Ax - m)*w + bbv);
        xsbuf[i & 3][i >> 2] = f2bf((xv - Ax)*w);
        if ((i & 7) == 7)
            *(uintx4*)(tr + t0 + (i & ~7)) = *(const uintx4*)trbuf;
        int uo = t - 12; uo = uo < 0 ? 0 : uo;
        int un = t + 13; un = un > 511 ? 511 : un;
        win += XT(un, ch) - XT(uo, ch);
    }
#pragma unroll
    for (int s4 = 0; s4 < 4; ++s4)
        *(uintx4*)(xsr + s4*128 + tp*8) = *(const uintx4*)xsbuf[s4];
}

// ---------------- fused 2-block MLP, transposed GEMMs, chunk=32, 40 KB LDS ----------------
// Wave owns 32 rows. GEMM1: Ht = W1c(A) x xs(B) -> lane holds 4 consecutive h ->
// b64 scratch stores. GEMM2: Yt = W2c(A) x H(B) -> lane holds 4 consecutive n ->
// b64 global stores. Weight slots DMA double-buffered; ONE barrier per chunk.
// LDS (u16): slot0 [0,8192) = W1c[32x128] @0 + W2c[2kh][128][16] @4096
//            slot1 [8192,16384) ; scratch [16384,20480) = 4 waves x 1024.
#define SCR 16384
__device__ __forceinline__ void stage_chunk(u16* lds, int slot,
    const u16* w1s, const u16* w2s, int hb, int wv, int lane)
{
#pragma unroll
    for (int i = 0; i < 2; ++i){
        int qq = (wv*2 + i)*64 + lane;
        // W1c image: [32 h][16 segs], seg s' = (s&8)|((s^h)&7)
        int h = qq >> 4, sp = qq & 15;
        int s = (sp & 8) | ((sp ^ h) & 7);
        dma16(w1s + (size_t)(hb + h)*128 + s*8, lds + slot + qq*8);
        // W2c image: [kh=2][128 n][2 segs], seg s' = s ^ (n&1)
        int kh = qq >> 8, n = (qq >> 1) & 127, s1 = qq & 1;
        int s2 = s1 ^ (n & 1);
        dma16(w2s + (size_t)n*512 + hb + kh*16 + s2*8, lds + slot + 4096 + qq*8);
    }
}
// scratch: row r (32/wave) x 8 slots of 4 bf16; slot g at (g ^ (r&7))
__device__ __forceinline__ void wr_h(u16* hscr, int grp, int rt, int cl, u32 lo, u32 hi){
    *(uintx2*)(hscr + (rt*16 + cl)*32 + (((grp ^ (cl & 7)) << 2))) = (uintx2){lo, hi};
}
__device__ __forceinline__ bf16x8 rd_h(const u16* hscr, int rt, int quad, int cl){
    int a0 = (rt*16 + cl)*32 + (((2*quad) ^ (cl & 7)) << 2);
    union { bf16x8 v; uintx2 p[2]; } u;
    u.p[0] = *(const uintx2*)(hscr + a0);
    u.p[1] = *(const uintx2*)(hscr + (a0 ^ 4));
    return u.v;
}

__global__ __launch_bounds__(256, 3) void mlp_fused_k(
    const u16* __restrict__ xs,
    const u16* __restrict__ BT1, const float* __restrict__ b11,
    const u16* __restrict__ BT2, const float* __restrict__ b12,
    const u16* __restrict__ BT3, const float* __restrict__ b21,
    const u16* __restrict__ BT4, const float* __restrict__ b22,
    u16* __restrict__ Afin)
{
    __shared__ u16 lds[20480];     // 40 KB -> 3 blocks/CU (reg-capped)
    const int tid = threadIdx.x;
    const int row0 = blockIdx.x * 128;
    const int lane = tid & 63;
    const int wv = tid >> 6;
    const int quad = lane >> 4, cl = lane & 15;
    const int wrow = row0 + wv*32;
    u16* hscr = lds + SCR + wv*1024;

    // A(xs)-as-B fragments, straight from global (L2/L3-warm from decomp)
    bf16x8 afrag[2][4];
#pragma unroll
    for (int rt = 0; rt < 2; ++rt)
#pragma unroll
        for (int ks = 0; ks < 4; ++ks)
            afrag[rt][ks] = *(const bf16x8*)(xs + (size_t)(wrow + rt*16 + cl)*128 + ks*32 + quad*8);

    stage_chunk(lds, 0, BT1, BT2, 0, wv, lane);   // chunk 0 -> slot0

    floatx4 Yacc[16];
#pragma unroll
    for (int i = 0; i < 16; ++i) Yacc[i] = (floatx4){0.f,0.f,0.f,0.f};
    floatx4 hacc[4];

    __syncthreads();                              // chunk 0 landed

    for (int g = 0; g < 32; ++g){
        const int cur = (g & 1) * 8192;
        if (g < 31){                              // DMA chunk g+1 into other slot
            const u16* w1s = ((g+1) & 16) ? BT3 : BT1;
            const u16* w2s = ((g+1) & 16) ? BT4 : BT2;
            stage_chunk(lds, 8192 - cur, w1s, w2s, ((g+1) & 15)*32, wv, lane);
        }
        const float* ba = (g & 16) ? b21 : b11;
        const int hoff = (g & 15) * 32;

        // GEMM1: Ht[h][r] = W1c x xs  (2 ht x 2 rt tiles, K=128)
#pragma unroll
        for (int i = 0; i < 4; ++i) hacc[i] = (floatx4){0.f,0.f,0.f,0.f};
#pragma unroll
        for (int ks = 0; ks < 4; ++ks)
#pragma unroll
            for (int ht = 0; ht < 2; ++ht){
                int h = ht*16 + cl;
                int s = ks*4 + quad;
                int sp = (s & 8) | ((s ^ h) & 7);
                bf16x8 w1f = *(const bf16x8*)(lds + cur + h*128 + sp*8);
                hacc[ht*2+0] = MFMA16(w1f, afrag[0][ks], hacc[ht*2+0]);
                hacc[ht*2+1] = MFMA16(w1f, afrag[1][ks], hacc[ht*2+1]);
            }
        // GELU + bias -> scratch (b64 stores, 4 consecutive h per lane-quad)
#pragma unroll
        for (int ht = 0; ht < 2; ++ht){
            floatx4 bv = *(const floatx4*)(ba + hoff + ht*16 + quad*4);
#pragma unroll
            for (int rt = 0; rt < 2; ++rt){
                floatx4 v = hacc[ht*2+rt];
                wr_h(hscr, ht*4 + quad, rt, cl,
                     pack2bf(fgelu(v[0]+bv[0]), fgelu(v[1]+bv[1])),
                     pack2bf(fgelu(v[2]+bv[2]), fgelu(v[3]+bv[3])));
            }
        }
        // GEMM2: Yt[n][r] += W2c x H  (8 nt x 2 rt tiles, K=32)
        {
            bf16x8 hfr0 = rd_h(hscr, 0, quad, cl);
            bf16x8 hfr1 = rd_h(hscr, 1, quad, cl);
#pragma unroll
            for (int nt = 0; nt < 8; ++nt){
                int n = nt*16 + cl;
                bf16x8 w2f = *(const bf16x8*)(lds + cur + 4096 + (quad >> 1)*2048
                                              + n*16 + (((quad & 1) ^ (n & 1)) << 3));
                Yacc[nt*2+0] = MFMA16(w2f, hfr0, Yacc[nt*2+0]);
                Yacc[nt*2+1] = MFMA16(w2f, hfr1, Yacc[nt*2+1]);
            }
        }
        __syncthreads();                          // slot reads done + DMA g+1 drained

        if (g == 15){
            // handoff: h1 = Yt + b12 -> scratch -> new afrag (4 passes of 32 k)
#pragma unroll
            for (int np = 0; np < 4; ++np){
#pragma unroll
                for (int nt2 = 0; nt2 < 2; ++nt2){
                    int nt = np*2 + nt2;
                    floatx4 bv = *(const floatx4*)(b12 + nt*16 + quad*4);
#pragma unroll
                    for (int rt = 0; rt < 2; ++rt){
                        floatx4 v = Yacc[nt*2+rt];
                        wr_h(hscr, nt2*4 + quad, rt, cl,
                             pack2bf(v[0]+bv[0], v[1]+bv[1]),
                             pack2bf(v[2]+bv[2], v[3]+bv[3]));
                    }
                }
#pragma unroll
                for (int rt = 0; rt < 2; ++rt)
                    afrag[rt][np] = rd_h(hscr, rt, quad, cl);
            }
#pragma unroll
            for (int i = 0; i < 16; ++i) Yacc[i] = (floatx4){0.f,0.f,0.f,0.f};
        }
    }

    // epilogue: h2 = Yt + b22 -> Afin[:, 512 + s*128 + n], b64 packed stores
#pragma unroll
    for (int rt = 0; rt < 2; ++rt){
        int gr = wrow + rt*16 + cl;
        size_t base = (size_t)(gr >> 2)*1024 + 512 + (size_t)(gr & 3)*128;
#pragma unroll
        for (int nt = 0; nt < 8; ++nt){
            int c0 = nt*16 + quad*4;
            floatx4 bv = *(const floatx4*)(b22 + c0);
            floatx4 v = Yacc[nt*2+rt];
            uintx2 pk = { pack2bf(v[0]+bv[0], v[1]+bv[1]),
                          pack2bf(v[2]+bv[2], v[3]+bv[3]) };
            *(uintx2*)(Afin + base + c0) = pk;
        }
    }
}

// ---------------- final fused-head GEMM, DMA double-buffered, XCD-grouped ----------------
__global__ __launch_bounds__(256, 3) void head_gemm_k(
    const u16* __restrict__ A, const u16* __restrict__ BT,
    float* __restrict__ Cf,
    const float* __restrict__ bias, const float* __restrict__ bias2,
    const float* __restrict__ rw, const float* __restrict__ rb,
    const float2* __restrict__ stats)
{
    __shared__ u16 lds[32768];    // A slices @0,@8192 ; B slices @16384,@24576
    const int id = blockIdx.x;
    const int xcd = id & 7, slot = id >> 3;
    const int g8 = slot / 3, j = slot - g8*3;
    const int by = xcd + 8*g8;
    if (by >= 321) return;
    const int row0 = by * 128, col0 = j * 128;

    const int tid = threadIdx.x;
    const int lane = tid & 63;
    const int wv = tid >> 6;
    const int wm = wv & 1, wn = wv >> 1;
    const int quad = lane >> 4, cl = lane & 15;

    const int qbase = wv*4*64 + lane;

#pragma unroll
    for (int i = 0; i < 4; ++i){
        int qq = qbase + i*64;
        int r = qq >> 3, p = qq & 7; int s = (p ^ r) & 7;
        dma16(A  + (size_t)(row0 + r)*1024 + s*8, lds + qq*8);
        dma16(BT + (size_t)(col0 + r)*1024 + s*8, lds + 16384 + qq*8);
    }
    __syncthreads();

    floatx4 acc[16];
#pragma unroll
    for (int i = 0; i < 16; ++i) acc[i] = (floatx4){0.f,0.f,0.f,0.f};

    for (int it = 0; it < 16; ++it){
        const int cur = (it & 1) * 8192;
        if (it < 15){
            const int nxt = ((it+1) & 1) * 8192;
            const int k0 = (it+1) * 64;
#pragma unroll
            for (int i = 0; i < 4; ++i){
                int qq = qbase + i*64;
                int r = qq >> 3, p = qq & 7; int s = (p ^ r) & 7;
                dma16(A  + (size_t)(row0 + r)*1024 + k0 + s*8, lds + nxt + qq*8);
                dma16(BT + (size_t)(col0 + r)*1024 + k0 + s*8, lds + 16384 + nxt + qq*8);
            }
        }
#pragma unroll
        for (int kk = 0; kk < 2; ++kk){
            bf16x8 af[4], bfr[4];
#pragma unroll
            for (int mt = 0; mt < 4; ++mt) af[mt]  = *(const bf16x8*)(lds + cur + swz64(wm*64 + mt*16 + cl, kk*4 + quad));
#pragma unroll
            for (int nt = 0; nt < 4; ++nt) bfr[nt] = *(const bf16x8*)(lds + 16384 + cur + swz64(wn*64 + nt*16 + cl, kk*4 + quad));
#pragma unroll
            for (int mt = 0; mt < 4; ++mt)
#pragma unroll
                for (int nt = 0; nt < 4; ++nt)
                    acc[mt*4+nt] = MFMA16(af[mt], bfr[nt], acc[mt*4+nt]);
        }
        __syncthreads();
    }

#pragma unroll
    for (int mt = 0; mt < 4; ++mt)
#pragma unroll
        for (int nt = 0; nt < 4; ++nt){
            floatx4 v = acc[mt*4+nt];
            int gc = col0 + wn*64 + nt*16 + cl;
            if (gc >= PREDD) continue;
            float bsum = bias[gc] + bias2[gc];
#pragma unroll
            for (int i = 0; i < 4; ++i){
                int gr = row0 + wm*64 + mt*16 + quad*4 + i;
                float val = v[i] + bsum;
                int bv2 = gr / CC;
                int c  = gr - bv2*CC;
                val = (val - rb[c]) / (rw[c] + 1e-10f);
                float2 st = stats[gr];
                val = val*st.y + st.x;
                Cf[(size_t)bv2*(PREDD*CC) + (size_t)gc*CC + c] = val;
            }
        }
}

extern "C" void kernel_launch(void* const* d_in, const int* in_sizes, int n_in,
                              void* d_out, int out_size, void* d_ws, size_t ws_size,
                              hipStream_t stream)
{
    const float* x   = (const float*)d_in[0];
    const float* rvw = (const float*)d_in[1];
    const float* rvb = (const float*)d_in[2];
    const float* W11 = (const float*)d_in[3];
    const float* b11 = (const float*)d_in[4];
    const float* W12 = (const float*)d_in[5];
    const float* b12 = (const float*)d_in[6];
    const float* W21 = (const float*)d_in[7];
    const float* b21 = (const float*)d_in[8];
    const float* W22 = (const float*)d_in[9];
    const float* b22 = (const float*)d_in[10];
    const float* Wtr = (const float*)d_in[11];
    const float* btr = (const float*)d_in[12];
    const float* Wse = (const float*)d_in[13];
    const float* bse = (const float*)d_in[14];
    float* out = (float*)d_out;

    char* ws = (char*)d_ws;
    u16* BT1 = (u16*)(ws + 0);            //  512x128 bf16
    u16* BT2 = (u16*)(ws + 131072);       //  128x512
    u16* BT3 = (u16*)(ws + 262144);       //  512x128
    u16* BT4 = (u16*)(ws + 393216);       //  128x512
    u16* BT5 = (u16*)(ws + 524288);       //  384x1024
    float2* stats = (float2*)(ws + 1310720);      // 41088 x {mean,std}
    u16* Afin = (u16*)(ws + 1639424);     // concat-A [41088][1024]: trend | sea
    u16* xs   = (u16*)(ws + 85787648);    // [164352][128] split seasonal

    hipLaunchKernelGGL(prep_k, dim3(1536), dim3(256), 0, stream,
                       W11, W12, W21, W22, Wtr, Wse, BT1, BT2, BT3, BT4, BT5);
    hipLaunchKernelGGL(decomp_k, dim3(128*21), dim3(256), 0, stream,
                       x, rvw, rvb, Afin, xs, stats);
    hipLaunchKernelGGL(mlp_fused_k, dim3(1284), dim3(256), 0, stream,
                       xs, BT1, b11, BT2, b12, BT3, b21, BT4, b22, Afin);
    hipLaunchKernelGGL(head_gemm_k, dim3(984), dim3(256), 0, stream,
                       Afin, BT5, out, btr, bse, rvw, rvb, stats);
}